// Round 6
// baseline (917.561 us; speedup 1.0000x reference)
//
#include <hip/hip_runtime.h>
#include <hip/hip_fp16.h>

#define N_ITEMS   100000
#define N_BASKETS 50000
#define NNZ       1000000
#define D         128

// ---------------- windowed CSR build: counting sort on key=(row,window) --------
// window = col >> 13  (8192 source rows * 256B fp16 = 2MB slice, fits XCD L2)
#define NBLK   256                         // chunks == blocks in hist/route
#define TPB    256
#define CH     ((NNZ + NBLK - 1) / NBLK)   // 3907 elements per chunk
#define COLSH  13
#define WIN_I  8                           // item matrix: cols < 50000  -> w in 0..6
#define WIN_B  16                          // basket matrix: cols < 100000 -> w in 0..12
#define LOGW_I 3
#define LOGW_B 4
#define NKEY   800000                      // N_ITEMS*WIN_I == N_BASKETS*WIN_B
#define NBUK2  3125                        // NKEY / 256 (exact)

// SpMM shape: persistent blocks, 13 rows per wave, window-outer loop
#define RPW    13

__device__ __forceinline__ int chunk_of_block() {
    return ((blockIdx.x & 7) << 5) | (blockIdx.x >> 3);
}

// pass 1a: per-(chunk,bucket) key counts. LDS atomics only.
__global__ __launch_bounds__(256) void k_bucket_hist(
        const int* __restrict__ b_rows, const int* __restrict__ b_cols,
        const int* __restrict__ i_rows, const int* __restrict__ i_cols,
        int* __restrict__ tableB, int* __restrict__ tableI) {
    __shared__ int cnt[NBUK2];
    int chunk = chunk_of_block();
    int s = chunk * CH, e = min(s + CH, NNZ);
    for (int j = threadIdx.x; j < NBUK2; j += TPB) cnt[j] = 0;
    __syncthreads();
    for (int i = s + (int)threadIdx.x; i < e; i += TPB) {
        int key = (b_rows[i] << LOGW_B) | (b_cols[i] >> COLSH);
        atomicAdd(&cnt[key >> 8], 1);
    }
    __syncthreads();
    for (int j = threadIdx.x; j < NBUK2; j += TPB) tableB[chunk * NBUK2 + j] = cnt[j];
    __syncthreads();
    for (int j = threadIdx.x; j < NBUK2; j += TPB) cnt[j] = 0;
    __syncthreads();
    for (int i = s + (int)threadIdx.x; i < e; i += TPB) {
        int key = (i_rows[i] << LOGW_I) | (i_cols[i] >> COLSH);
        atomicAdd(&cnt[key >> 8], 1);
    }
    __syncthreads();
    for (int j = threadIdx.x; j < NBUK2; j += TPB) tableI[chunk * NBUK2 + j] = cnt[j];
}

// pass 2a: per-bucket exclusive scan over chunk counts (in place), bucket total out.
__global__ __launch_bounds__(256) void k_col_scan(int* __restrict__ tableB,
                                                  int* __restrict__ tableI,
                                                  int* __restrict__ tot) {
    __shared__ int lds[NBLK];
    int id = blockIdx.x;
    int m = id / NBUK2, b = id % NBUK2;
    int* tbl = m ? tableI : tableB;
    int t = threadIdx.x;
    int v = tbl[t * NBUK2 + b];
    lds[t] = v;
    __syncthreads();
    for (int o = 1; o < NBLK; o <<= 1) {
        int tv = (t >= o) ? lds[t - o] : 0;
        __syncthreads();
        lds[t] += tv;
        __syncthreads();
    }
    tbl[t * NBUK2 + b] = lds[t] - v;
    if (t == NBLK - 1) tot[m * NBUK2 + b] = lds[t];
}

// pass 2b: exclusive scan of 3125 bucket totals per matrix (1 block per matrix).
__global__ __launch_bounds__(256) void k_base_scan(const int* __restrict__ tot,
                                                   int* __restrict__ base) {
    __shared__ int lds[256];
    int m = blockIdx.x;
    int t = threadIdx.x;
    int carry = 0;
    for (int c = 0; c < NBUK2; c += 256) {
        int idx = c + t;
        int v = (idx < NBUK2) ? tot[m * NBUK2 + idx] : 0;
        lds[t] = v;
        __syncthreads();
        for (int o = 1; o < 256; o <<= 1) {
            int tv = (t >= o) ? lds[t - o] : 0;
            __syncthreads();
            lds[t] += tv;
            __syncthreads();
        }
        if (idx < NBUK2) base[m * NBUK2 + idx] = carry + lds[t] - v;
        int tot_c = lds[255];
        __syncthreads();
        carry += tot_c;
    }
}

// pass 1b: route COO into bucket-grouped staging (key carried). LDS cursors only.
__global__ __launch_bounds__(256) void k_route(
        const int* __restrict__ b_rows, const int* __restrict__ b_cols,
        const float* __restrict__ b_vals,
        const int* __restrict__ i_rows, const int* __restrict__ i_cols,
        const float* __restrict__ i_vals,
        const int* __restrict__ tableB, const int* __restrict__ tableI,
        const int* __restrict__ base,
        int* __restrict__ stg_keyB, int2* __restrict__ stg_cvB,
        int* __restrict__ stg_keyI, int2* __restrict__ stg_cvI) {
    __shared__ int cur[NBUK2];
    int chunk = chunk_of_block();
    int s = chunk * CH, e = min(s + CH, NNZ);
    for (int j = threadIdx.x; j < NBUK2; j += TPB)
        cur[j] = base[j] + tableB[chunk * NBUK2 + j];
    __syncthreads();
    for (int i = s + (int)threadIdx.x; i < e; i += TPB) {
        int r = b_rows[i];
        int c = b_cols[i];
        float v = b_vals[i];
        int key = (r << LOGW_B) | (c >> COLSH);
        int p = atomicAdd(&cur[key >> 8], 1);   // LDS atomic
        stg_keyB[p] = key;
        stg_cvB[p] = make_int2(c, __float_as_int(v));
    }
    __syncthreads();
    for (int j = threadIdx.x; j < NBUK2; j += TPB)
        cur[j] = base[NBUK2 + j] + tableI[chunk * NBUK2 + j];
    __syncthreads();
    for (int i = s + (int)threadIdx.x; i < e; i += TPB) {
        int r = i_rows[i];
        int c = i_cols[i];
        float v = i_vals[i];
        int key = (r << LOGW_I) | (c >> COLSH);
        int p = atomicAdd(&cur[key >> 8], 1);   // LDS atomic
        stg_keyI[p] = key;
        stg_cvI[p] = make_int2(c, __float_as_int(v));
    }
}

// pass 3: per-bucket counting sort over 256 local keys -> final ev + rp2.
__global__ __launch_bounds__(256) void k_bucket_sort(
        const int* __restrict__ stg_keyB, const int2* __restrict__ stg_cvB,
        const int* __restrict__ stg_keyI, const int2* __restrict__ stg_cvI,
        const int* __restrict__ base, const int* __restrict__ tot,
        int* __restrict__ rp2B, int* __restrict__ rp2I,
        int2* __restrict__ b_ev, int2* __restrict__ i_ev) {
    __shared__ int hist[256];
    __shared__ int scn[256];
    __shared__ int cursor[256];
    int id = blockIdx.x;
    int m = id / NBUK2, b = id % NBUK2;
    const int*  skey = m ? stg_keyI : stg_keyB;
    const int2* scv  = m ? stg_cvI  : stg_cvB;
    int2* ev = m ? i_ev : b_ev;
    int*  rp = m ? rp2I : rp2B;
    int keybase = b << 8;
    int seg = base[m * NBUK2 + b];
    int cnt = tot[m * NBUK2 + b];
    int t = threadIdx.x;

    hist[t] = 0;
    __syncthreads();
    for (int i = t; i < cnt; i += TPB)
        atomicAdd(&hist[skey[seg + i] - keybase], 1);
    __syncthreads();
    int v = hist[t];
    scn[t] = v;
    __syncthreads();
    for (int o = 1; o < 256; o <<= 1) {
        int tv = (t >= o) ? scn[t - o] : 0;
        __syncthreads();
        scn[t] += tv;
        __syncthreads();
    }
    int excl = scn[t] - v;
    rp[keybase + t] = seg + excl;
    if (t == 0 && b == NBUK2 - 1) rp[NKEY] = NNZ;
    cursor[t] = excl;
    __syncthreads();
    for (int i = t; i < cnt; i += TPB) {
        int key = skey[seg + i];
        int p = atomicAdd(&cursor[key - keybase], 1);   // LDS atomic
        ev[seg + p] = scv[seg + i];
    }
}

// ---------------- x -> fp16 conversion (once) ----------------
__global__ __launch_bounds__(256) void k_cvt(const float2* __restrict__ xin,
                                             __half2* __restrict__ xout) {
    const int n = N_ITEMS * D / 2;
    int i = blockIdx.x * blockDim.x + threadIdx.x;
    int stride = gridDim.x * blockDim.x;
    for (; i < n; i += stride) xout[i] = __float22half2_rn(xin[i]);
}

// ---------------- windowed persistent CSR SpMM ----------------
// One co-resident generation of blocks; each wave owns RPW=13 rows (fp32 acc in
// registers, statically indexed); outer loop over column windows (2MB fp16 slices)
// keeps all blocks gathering from the same L2-resident slice (soft lockstep).
// MODE 1: basket L1: out16 = h(acc); outf  = acc
// MODE 2: basket L2: out16 = h(acc); outf += acc
// MODE 3: basket L3: out16 = h(acc); outf  = (outf+acc)/3
// MODE 0: item L1/L2: out16 = h(acc)
// MODE 4: item L3:   outf = (a0 + f(a1) + f(a2) + acc)/4
template<int MODE, int W>
__global__ __launch_bounds__(256, 8) void k_spmm_win(
        const int* __restrict__ rp2, const int2* __restrict__ ev,
        const void* __restrict__ src,
        void* __restrict__ out16, float* __restrict__ outf,
        const float* __restrict__ a0, const void* __restrict__ a1,
        const void* __restrict__ a2, int n_rows) {
    int wv   = threadIdx.x >> 6;
    int lane = threadIdx.x & 63;
    int rbase = (blockIdx.x * 4 + wv) * RPW;
    if (rbase >= n_rows) return;

    const char* dbase = reinterpret_cast<const char*>(src) + (size_t)lane * 4;
    float2 acc[RPW];
    #pragma unroll
    for (int i = 0; i < RPW; ++i) acc[i] = make_float2(0.f, 0.f);

    for (int w = 0; w < W; ++w) {
        #pragma unroll
        for (int i = 0; i < RPW; ++i) {
            int r = rbase + i;
            if (r < n_rows) {
                int key = r * W + w;
                int beg = __builtin_amdgcn_readfirstlane(rp2[key]);
                int end = __builtin_amdgcn_readfirstlane(rp2[key + 1]);
                for (int e = beg; e < end; ++e) {
                    int2 p = ev[e];
                    __half2 h = *reinterpret_cast<const __half2*>(
                        dbase + ((size_t)p.x << 8));
                    float2 d = __half22float2(h);
                    float v = __int_as_float(p.y);
                    acc[i].x = fmaf(v, d.x, acc[i].x);
                    acc[i].y = fmaf(v, d.y, acc[i].y);
                }
            }
        }
    }

    #pragma unroll
    for (int i = 0; i < RPW; ++i) {
        int r = rbase + i;
        if (r >= n_rows) continue;
        size_t o = (size_t)r * 64 + (size_t)lane;   // half2 / float2 index
        float2 a = acc[i];
        if (MODE == 0 || MODE == 1 || MODE == 2 || MODE == 3) {
            reinterpret_cast<__half2*>(out16)[o] = __float22half2_rn(a);
        }
        if (MODE == 1) {
            reinterpret_cast<float2*>(outf)[o] = a;
        } else if (MODE == 2) {
            float2 s = reinterpret_cast<const float2*>(outf)[o];
            s.x += a.x; s.y += a.y;
            reinterpret_cast<float2*>(outf)[o] = s;
        } else if (MODE == 3) {
            float2 s = reinterpret_cast<const float2*>(outf)[o];
            s.x = (s.x + a.x) * (1.0f / 3.0f);
            s.y = (s.y + a.y) * (1.0f / 3.0f);
            reinterpret_cast<float2*>(outf)[o] = s;
        } else if (MODE == 4) {
            float2 s0 = reinterpret_cast<const float2*>(a0)[o];
            float2 c1 = __half22float2(reinterpret_cast<const __half2*>(a1)[o]);
            float2 c2 = __half22float2(reinterpret_cast<const __half2*>(a2)[o]);
            float2 rr;
            rr.x = (s0.x + c1.x + c2.x + a.x) * 0.25f;
            rr.y = (s0.y + c1.y + c2.y + a.y) * 0.25f;
            reinterpret_cast<float2*>(outf)[o] = rr;
        }
    }
}

extern "C" void kernel_launch(void* const* d_in, const int* in_sizes, int n_in,
                              void* d_out, int out_size, void* d_ws, size_t ws_size,
                              hipStream_t stream) {
    const float* x      = (const float*)d_in[0];
    const int*   b_rows = (const int*)  d_in[1];
    const int*   b_cols = (const int*)  d_in[2];
    const float* b_vals = (const float*)d_in[3];
    const int*   i_rows = (const int*)  d_in[4];
    const int*   i_cols = (const int*)  d_in[5];
    const float* i_vals = (const float*)d_in[6];

    float* out        = (float*)d_out;
    float* out_item   = out;                              // [N_ITEMS * D]
    float* out_basket = out + (size_t)N_ITEMS * D;        // [N_BASKETS * D]

    char* ws = (char*)d_ws;
    size_t off = 0;
    auto alloc = [&](size_t bytes) -> char* {
        char* p = ws + off;
        off = (off + bytes + 255) & ~(size_t)255;
        return p;
    };
    int*   tot       = (int*)  alloc(2 * NBUK2 * sizeof(int));
    int*   base      = (int*)  alloc(2 * NBUK2 * sizeof(int));
    int*   rp2B      = (int*)  alloc((NKEY + 1) * sizeof(int));   // 3.2 MB
    int*   rp2I      = (int*)  alloc((NKEY + 1) * sizeof(int));   // 3.2 MB
    int2*  b_ev      = (int2*) alloc((size_t)NNZ * sizeof(int2)); // 8 MB
    int2*  i_ev      = (int2*) alloc((size_t)NNZ * sizeof(int2)); // 8 MB
    void*  basket16  = (void*) alloc((size_t)N_BASKETS * D * 2);  // 12.8 MB
    // region R1 (25.6 MB): tables (build) -> x16 (cvt..basketL1) -> cur2 (itemL2..)
    char*  R1        = alloc((size_t)N_ITEMS * D * 2);
    int*   tableB    = (int*)R1;                                   // 3.2 MB
    int*   tableI    = (int*)(R1 + (size_t)NBLK * NBUK2 * sizeof(int));
    void*  x16       = (void*)R1;
    void*  cur2_16   = (void*)R1;
    // region R2 (25.6 MB): staging (build) -> cur1 (itemL1..)
    char*  R2        = alloc((size_t)N_ITEMS * D * 2);
    int*   stg_keyB  = (int*) R2;                                  // 4 MB
    int2*  stg_cvB   = (int2*)(R2 + (size_t)NNZ * 4);              // 8 MB
    int*   stg_keyI  = (int*) (R2 + (size_t)NNZ * 12);             // 4 MB
    int2*  stg_cvI   = (int2*)(R2 + (size_t)NNZ * 16);             // 8 MB
    void*  cur1_16   = (void*)R2;
    (void)ws_size; (void)in_sizes; (void)n_in; (void)out_size;

    // -------- atomic-free windowed CSR build --------
    k_bucket_hist<<<NBLK, TPB, 0, stream>>>(b_rows, b_cols, i_rows, i_cols,
                                            tableB, tableI);
    k_col_scan<<<2 * NBUK2, NBLK, 0, stream>>>(tableB, tableI, tot);
    k_base_scan<<<2, 256, 0, stream>>>(tot, base);
    k_route<<<NBLK, TPB, 0, stream>>>(b_rows, b_cols, b_vals,
                                      i_rows, i_cols, i_vals,
                                      tableB, tableI, base,
                                      stg_keyB, stg_cvB, stg_keyI, stg_cvI);
    k_bucket_sort<<<2 * NBUK2, 256, 0, stream>>>(stg_keyB, stg_cvB, stg_keyI, stg_cvI,
                                                 base, tot,
                                                 rp2B, rp2I, b_ev, i_ev);
    // x -> fp16 (after route: x16 region aliases the now-dead tables)
    k_cvt<<<2048, 256, 0, stream>>>(reinterpret_cast<const float2*>(x),
                                    reinterpret_cast<__half2*>(x16));

    const int GB = ((N_BASKETS + RPW - 1) / RPW + 3) / 4;   // 962 blocks
    const int GI = ((N_ITEMS  + RPW - 1) / RPW + 3) / 4;    // 1924 blocks

    // -------- layer 1 --------
    k_spmm_win<1, WIN_B><<<GB, 256, 0, stream>>>(rp2B, b_ev, x16, basket16, out_basket,
                                                 nullptr, nullptr, nullptr, N_BASKETS);
    k_spmm_win<0, WIN_I><<<GI, 256, 0, stream>>>(rp2I, i_ev, basket16, cur1_16, nullptr,
                                                 nullptr, nullptr, nullptr, N_ITEMS);
    // -------- layer 2 --------
    k_spmm_win<2, WIN_B><<<GB, 256, 0, stream>>>(rp2B, b_ev, cur1_16, basket16, out_basket,
                                                 nullptr, nullptr, nullptr, N_BASKETS);
    k_spmm_win<0, WIN_I><<<GI, 256, 0, stream>>>(rp2I, i_ev, basket16, cur2_16, nullptr,
                                                 nullptr, nullptr, nullptr, N_ITEMS);
    // -------- layer 3 --------
    k_spmm_win<3, WIN_B><<<GB, 256, 0, stream>>>(rp2B, b_ev, cur2_16, basket16, out_basket,
                                                 nullptr, nullptr, nullptr, N_BASKETS);
    k_spmm_win<4, WIN_I><<<GI, 256, 0, stream>>>(rp2I, i_ev, basket16, nullptr, out_item,
                                                 x, cur1_16, cur2_16, N_ITEMS);
}

// Round 7
// 584.971 us; speedup vs baseline: 1.5686x; 1.5686x over previous
//
#include <hip/hip_runtime.h>
#include <hip/hip_fp16.h>

#define N_ITEMS   100000
#define N_BASKETS 50000
#define NNZ       1000000
#define D         128

// ---------------- windowed CSR build: counting sort on key=(row,window) --------
// window = col >> 13 (8192 source rows x 256B fp16 = 2MB slice, fits XCD L2)
#define NBLK   256                         // chunks == blocks in hist/route
#define TPB    256
#define CH     ((NNZ + NBLK - 1) / NBLK)   // 3907 elements per chunk
#define COLSH  13
#define W_B    13       // basket matrix: cols < 100000 -> w in 0..12
#define W_I    7        // item matrix:   cols < 50000  -> w in 0..6
#define NBUK_B 2540     // ceil(50000*13/256)
#define NBUK_I 2735     // ceil(100000*7/256)
#define NKEYPAD_B (NBUK_B * 256)   // 650240
#define NKEYPAD_I (NBUK_I * 256)   // 700160
#define NBUK_MAX 2735

// SpMM shape: one co-resident generation, RPW rows per wave, window-outer loop
#define RPW_B  7        // grid 1786 blocks (<=2048 co-resident at 8 blk/CU)
#define RPW_I  13       // grid 1924 blocks

__device__ __forceinline__ int chunk_of_block() {
    return ((blockIdx.x & 7) << 5) | (blockIdx.x >> 3);
}

// pass 1a: per-(chunk,bucket) key counts. LDS atomics only.
__global__ __launch_bounds__(256) void k_bucket_hist(
        const int* __restrict__ b_rows, const int* __restrict__ b_cols,
        const int* __restrict__ i_rows, const int* __restrict__ i_cols,
        int* __restrict__ tableB, int* __restrict__ tableI) {
    __shared__ int cnt[NBUK_MAX];
    int chunk = chunk_of_block();
    int s = chunk * CH, e = min(s + CH, NNZ);
    for (int j = threadIdx.x; j < NBUK_B; j += TPB) cnt[j] = 0;
    __syncthreads();
    for (int i = s + (int)threadIdx.x; i < e; i += TPB) {
        int key = b_rows[i] * W_B + (b_cols[i] >> COLSH);
        atomicAdd(&cnt[key >> 8], 1);
    }
    __syncthreads();
    for (int j = threadIdx.x; j < NBUK_B; j += TPB) tableB[chunk * NBUK_B + j] = cnt[j];
    __syncthreads();
    for (int j = threadIdx.x; j < NBUK_I; j += TPB) cnt[j] = 0;
    __syncthreads();
    for (int i = s + (int)threadIdx.x; i < e; i += TPB) {
        int key = i_rows[i] * W_I + (i_cols[i] >> COLSH);
        atomicAdd(&cnt[key >> 8], 1);
    }
    __syncthreads();
    for (int j = threadIdx.x; j < NBUK_I; j += TPB) tableI[chunk * NBUK_I + j] = cnt[j];
}

// pass 2a: per-bucket exclusive scan over the 256 chunk counts; bucket total out.
__global__ __launch_bounds__(256) void k_col_scan(int* __restrict__ tableB,
                                                  int* __restrict__ tableI,
                                                  int* __restrict__ totB,
                                                  int* __restrict__ totI) {
    __shared__ int lds[NBLK];
    int id = blockIdx.x;
    int* tbl; int* tot; int b; int nbuk;
    if (id < NBUK_B) { tbl = tableB; tot = totB; b = id;          nbuk = NBUK_B; }
    else             { tbl = tableI; tot = totI; b = id - NBUK_B; nbuk = NBUK_I; }
    int t = threadIdx.x;               // == chunk id
    int v = tbl[t * nbuk + b];
    lds[t] = v;
    __syncthreads();
    for (int o = 1; o < NBLK; o <<= 1) {
        int tv = (t >= o) ? lds[t - o] : 0;
        __syncthreads();
        lds[t] += tv;
        __syncthreads();
    }
    tbl[t * nbuk + b] = lds[t] - v;    // exclusive offset of chunk t within bucket b
    if (t == NBLK - 1) tot[b] = lds[t];
}

// pass 2b: chunked exclusive scan of bucket totals -> bucket element bases.
__global__ __launch_bounds__(256) void k_base_scan(const int* __restrict__ totB,
                                                   const int* __restrict__ totI,
                                                   int* __restrict__ baseB,
                                                   int* __restrict__ baseI) {
    __shared__ int lds[256];
    const int* tot; int* base; int n;
    if (blockIdx.x == 0) { tot = totB; base = baseB; n = NBUK_B; }
    else                 { tot = totI; base = baseI; n = NBUK_I; }
    int t = threadIdx.x;
    int carry = 0;
    for (int c = 0; c < n; c += 256) {
        int idx = c + t;
        int v = (idx < n) ? tot[idx] : 0;
        lds[t] = v;
        __syncthreads();
        for (int o = 1; o < 256; o <<= 1) {
            int tv = (t >= o) ? lds[t - o] : 0;
            __syncthreads();
            lds[t] += tv;
            __syncthreads();
        }
        if (idx < n) base[idx] = carry + lds[t] - v;
        int tc = lds[255];
        __syncthreads();
        carry += tc;
    }
}

// pass 1b: route COO into bucket-grouped staging (key carried). LDS cursors only.
__global__ __launch_bounds__(256) void k_route(
        const int* __restrict__ b_rows, const int* __restrict__ b_cols,
        const float* __restrict__ b_vals,
        const int* __restrict__ i_rows, const int* __restrict__ i_cols,
        const float* __restrict__ i_vals,
        const int* __restrict__ tableB, const int* __restrict__ tableI,
        const int* __restrict__ baseB, const int* __restrict__ baseI,
        int* __restrict__ stg_keyB, int2* __restrict__ stg_cvB,
        int* __restrict__ stg_keyI, int2* __restrict__ stg_cvI) {
    __shared__ int cur[NBUK_MAX];
    int chunk = chunk_of_block();
    int s = chunk * CH, e = min(s + CH, NNZ);
    for (int j = threadIdx.x; j < NBUK_B; j += TPB)
        cur[j] = baseB[j] + tableB[chunk * NBUK_B + j];
    __syncthreads();
    for (int i = s + (int)threadIdx.x; i < e; i += TPB) {
        int r = b_rows[i];
        int c = b_cols[i];
        float v = b_vals[i];
        int key = r * W_B + (c >> COLSH);
        int p = atomicAdd(&cur[key >> 8], 1);   // LDS atomic
        stg_keyB[p] = key;
        stg_cvB[p] = make_int2(c, __float_as_int(v));
    }
    __syncthreads();
    for (int j = threadIdx.x; j < NBUK_I; j += TPB)
        cur[j] = baseI[j] + tableI[chunk * NBUK_I + j];
    __syncthreads();
    for (int i = s + (int)threadIdx.x; i < e; i += TPB) {
        int r = i_rows[i];
        int c = i_cols[i];
        float v = i_vals[i];
        int key = r * W_I + (c >> COLSH);
        int p = atomicAdd(&cur[key >> 8], 1);   // LDS atomic
        stg_keyI[p] = key;
        stg_cvI[p] = make_int2(c, __float_as_int(v));
    }
}

// pass 3: per-bucket counting sort over 256 local keys -> final ev + rp2.
__global__ __launch_bounds__(256) void k_bucket_sort(
        const int* __restrict__ stg_keyB, const int2* __restrict__ stg_cvB,
        const int* __restrict__ stg_keyI, const int2* __restrict__ stg_cvI,
        const int* __restrict__ baseB, const int* __restrict__ baseI,
        const int* __restrict__ totB, const int* __restrict__ totI,
        int* __restrict__ rp2B, int* __restrict__ rp2I,
        int2* __restrict__ b_ev, int2* __restrict__ i_ev) {
    __shared__ int hist[256];
    __shared__ int scn[256];
    __shared__ int cursor[256];
    int id = blockIdx.x;
    const int* skey; const int2* scv; int* rp; int2* ev;
    const int* base; const int* tot; int b; int nbuk; int nkeypad;
    if (id < NBUK_B) {
        skey = stg_keyB; scv = stg_cvB; rp = rp2B; ev = b_ev;
        base = baseB; tot = totB; b = id; nbuk = NBUK_B; nkeypad = NKEYPAD_B;
    } else {
        skey = stg_keyI; scv = stg_cvI; rp = rp2I; ev = i_ev;
        base = baseI; tot = totI; b = id - NBUK_B; nbuk = NBUK_I; nkeypad = NKEYPAD_I;
    }
    int keybase = b << 8;
    int seg = base[b];
    int cnt = tot[b];
    int t = threadIdx.x;

    hist[t] = 0;
    __syncthreads();
    for (int i = t; i < cnt; i += TPB)
        atomicAdd(&hist[skey[seg + i] - keybase], 1);
    __syncthreads();
    int v = hist[t];
    scn[t] = v;
    __syncthreads();
    for (int o = 1; o < 256; o <<= 1) {
        int tv = (t >= o) ? scn[t - o] : 0;
        __syncthreads();
        scn[t] += tv;
        __syncthreads();
    }
    int excl = scn[t] - v;
    rp[keybase + t] = seg + excl;                 // padded keys -> seg+cnt (correct)
    if (t == 0 && b == nbuk - 1) rp[nkeypad] = NNZ;
    cursor[t] = excl;
    __syncthreads();
    for (int i = t; i < cnt; i += TPB) {
        int key = skey[seg + i];
        int p = atomicAdd(&cursor[key - keybase], 1);   // LDS atomic
        ev[seg + p] = scv[seg + i];
    }
}

// ---------------- x -> fp16 conversion (once) ----------------
__global__ __launch_bounds__(256) void k_cvt(const float2* __restrict__ xin,
                                             __half2* __restrict__ xout) {
    const int n = N_ITEMS * D / 2;
    int i = blockIdx.x * blockDim.x + threadIdx.x;
    int stride = gridDim.x * blockDim.x;
    for (; i < n; i += stride) xout[i] = __float22half2_rn(xin[i]);
}

// ---------------- windowed persistent CSR SpMM ----------------
// One co-resident generation; each wave owns RPW rows (fp32 acc in registers,
// statically unrolled); outer loop over 2MB source windows keeps all resident
// waves gathering from the same L2-resident slice. Segment bounds for a wave's
// rows are CONTIGUOUS keys -> bulk-loaded to LDS with 2 coalesced reads, then
// each segment costs one broadcast ds_read pair (fixes r6's scalar-load chains).
// MODE 1: basket L1: out16 = h(acc); outf  = acc
// MODE 2: basket L2: out16 = h(acc); outf += acc
// MODE 3: basket L3: out16 = h(acc); outf  = (outf+acc)/3
// MODE 0: item L1/L2: out16 = h(acc)
// MODE 4: item L3:   outf = (a0 + f(a1) + f(a2) + acc)/4
template<int MODE, int W, int RPW>
__global__ __launch_bounds__(256, 8) void k_spmm_win(
        const int* __restrict__ rp2, const int2* __restrict__ ev,
        const void* __restrict__ src,
        void* __restrict__ out16, float* __restrict__ outf,
        const float* __restrict__ a0, const void* __restrict__ a1,
        const void* __restrict__ a2, int n_rows, int nkeypad) {
    __shared__ int bnd[4][RPW * W + 1];
    int wv   = threadIdx.x >> 6;
    int lane = threadIdx.x & 63;
    int rbase = (blockIdx.x * 4 + wv) * RPW;
    int kbase = rbase * W;
    const int nb = RPW * W + 1;
    for (int j = lane; j < nb; j += 64)
        bnd[wv][j] = rp2[min(kbase + j, nkeypad)];   // clamp: tail waves read NNZ
    __syncthreads();   // no early return before this (all waves participate)

    const char* dbase = reinterpret_cast<const char*>(src) + (size_t)lane * 4;
    float2 acc[RPW];
    #pragma unroll
    for (int i = 0; i < RPW; ++i) acc[i] = make_float2(0.f, 0.f);

    for (int w = 0; w < W; ++w) {
        #pragma unroll
        for (int i = 0; i < RPW; ++i) {
            int beg = bnd[wv][i * W + w];
            int end = bnd[wv][i * W + w + 1];
            int e = beg;
            for (; e + 2 <= end; e += 2) {          // depth-2 pipeline (avg seg ~1.5)
                int2 p0 = ev[e], p1 = ev[e + 1];
                __half2 h0 = *reinterpret_cast<const __half2*>(dbase + ((size_t)p0.x << 8));
                __half2 h1 = *reinterpret_cast<const __half2*>(dbase + ((size_t)p1.x << 8));
                float2 d0 = __half22float2(h0);
                float2 d1 = __half22float2(h1);
                float v0 = __int_as_float(p0.y), v1 = __int_as_float(p1.y);
                acc[i].x = fmaf(v0, d0.x, acc[i].x); acc[i].y = fmaf(v0, d0.y, acc[i].y);
                acc[i].x = fmaf(v1, d1.x, acc[i].x); acc[i].y = fmaf(v1, d1.y, acc[i].y);
            }
            if (e < end) {
                int2 p = ev[e];
                __half2 h = *reinterpret_cast<const __half2*>(dbase + ((size_t)p.x << 8));
                float2 d = __half22float2(h);
                float v = __int_as_float(p.y);
                acc[i].x = fmaf(v, d.x, acc[i].x); acc[i].y = fmaf(v, d.y, acc[i].y);
            }
        }
    }

    #pragma unroll
    for (int i = 0; i < RPW; ++i) {
        int r = rbase + i;
        if (r >= n_rows) continue;
        size_t o = (size_t)r * 64 + (size_t)lane;   // half2 / float2 index
        float2 a = acc[i];
        if (MODE == 0 || MODE == 1 || MODE == 2 || MODE == 3) {
            reinterpret_cast<__half2*>(out16)[o] = __float22half2_rn(a);
        }
        if (MODE == 1) {
            reinterpret_cast<float2*>(outf)[o] = a;
        } else if (MODE == 2) {
            float2 s = reinterpret_cast<const float2*>(outf)[o];
            s.x += a.x; s.y += a.y;
            reinterpret_cast<float2*>(outf)[o] = s;
        } else if (MODE == 3) {
            float2 s = reinterpret_cast<const float2*>(outf)[o];
            s.x = (s.x + a.x) * (1.0f / 3.0f);
            s.y = (s.y + a.y) * (1.0f / 3.0f);
            reinterpret_cast<float2*>(outf)[o] = s;
        } else if (MODE == 4) {
            float2 s0 = reinterpret_cast<const float2*>(a0)[o];
            float2 c1 = __half22float2(reinterpret_cast<const __half2*>(a1)[o]);
            float2 c2 = __half22float2(reinterpret_cast<const __half2*>(a2)[o]);
            float2 rr;
            rr.x = (s0.x + c1.x + c2.x + a.x) * 0.25f;
            rr.y = (s0.y + c1.y + c2.y + a.y) * 0.25f;
            reinterpret_cast<float2*>(outf)[o] = rr;
        }
    }
}

extern "C" void kernel_launch(void* const* d_in, const int* in_sizes, int n_in,
                              void* d_out, int out_size, void* d_ws, size_t ws_size,
                              hipStream_t stream) {
    const float* x      = (const float*)d_in[0];
    const int*   b_rows = (const int*)  d_in[1];
    const int*   b_cols = (const int*)  d_in[2];
    const float* b_vals = (const float*)d_in[3];
    const int*   i_rows = (const int*)  d_in[4];
    const int*   i_cols = (const int*)  d_in[5];
    const float* i_vals = (const float*)d_in[6];

    float* out        = (float*)d_out;
    float* out_item   = out;                              // [N_ITEMS * D]
    float* out_basket = out + (size_t)N_ITEMS * D;        // [N_BASKETS * D]

    char* ws = (char*)d_ws;
    size_t off = 0;
    auto alloc = [&](size_t bytes) -> char* {
        char* p = ws + off;
        off = (off + bytes + 255) & ~(size_t)255;
        return p;
    };
    int*   totB      = (int*)  alloc(NBUK_B * sizeof(int));
    int*   totI      = (int*)  alloc(NBUK_I * sizeof(int));
    int*   baseB     = (int*)  alloc(NBUK_B * sizeof(int));
    int*   baseI     = (int*)  alloc(NBUK_I * sizeof(int));
    int*   rp2B      = (int*)  alloc((NKEYPAD_B + 1) * sizeof(int));  // 2.6 MB
    int*   rp2I      = (int*)  alloc((NKEYPAD_I + 1) * sizeof(int));  // 2.8 MB
    int2*  b_ev      = (int2*) alloc((size_t)NNZ * sizeof(int2));     // 8 MB
    int2*  i_ev      = (int2*) alloc((size_t)NNZ * sizeof(int2));     // 8 MB
    void*  basket16  = (void*) alloc((size_t)N_BASKETS * D * 2);      // 12.8 MB
    // region R1 (25.6 MB): tables (build) -> x16 (cvt..basketL1) -> cur2 (itemL2..)
    char*  R1        = alloc((size_t)N_ITEMS * D * 2);
    int*   tableB    = (int*)R1;                                      // 2.6 MB
    int*   tableI    = (int*)(R1 + (size_t)NBLK * NBUK_B * sizeof(int)); // 2.8 MB
    void*  x16       = (void*)R1;
    void*  cur2_16   = (void*)R1;
    // region R2 (25.6 MB): staging (build) -> cur1 (itemL1..)
    char*  R2        = alloc((size_t)N_ITEMS * D * 2);
    int*   stg_keyB  = (int*) R2;                                     // 4 MB
    int2*  stg_cvB   = (int2*)(R2 + (size_t)NNZ * 4);                 // 8 MB
    int*   stg_keyI  = (int*) (R2 + (size_t)NNZ * 12);                // 4 MB
    int2*  stg_cvI   = (int2*)(R2 + (size_t)NNZ * 16);                // 8 MB
    void*  cur1_16   = (void*)R2;
    (void)ws_size; (void)in_sizes; (void)n_in; (void)out_size;

    // -------- atomic-free windowed CSR build --------
    k_bucket_hist<<<NBLK, TPB, 0, stream>>>(b_rows, b_cols, i_rows, i_cols,
                                            tableB, tableI);
    k_col_scan<<<NBUK_B + NBUK_I, NBLK, 0, stream>>>(tableB, tableI, totB, totI);
    k_base_scan<<<2, 256, 0, stream>>>(totB, totI, baseB, baseI);
    k_route<<<NBLK, TPB, 0, stream>>>(b_rows, b_cols, b_vals,
                                      i_rows, i_cols, i_vals,
                                      tableB, tableI, baseB, baseI,
                                      stg_keyB, stg_cvB, stg_keyI, stg_cvI);
    k_bucket_sort<<<NBUK_B + NBUK_I, 256, 0, stream>>>(stg_keyB, stg_cvB,
                                                       stg_keyI, stg_cvI,
                                                       baseB, baseI, totB, totI,
                                                       rp2B, rp2I, b_ev, i_ev);
    // x -> fp16 (tables dead after route; x16 aliases them)
    k_cvt<<<2048, 256, 0, stream>>>(reinterpret_cast<const float2*>(x),
                                    reinterpret_cast<__half2*>(x16));

    const int GB = (N_BASKETS + RPW_B * 4 - 1) / (RPW_B * 4);  // 1786 blocks
    const int GI = (N_ITEMS  + RPW_I * 4 - 1) / (RPW_I * 4);   // 1924 blocks

    // -------- layer 1 --------
    k_spmm_win<1, W_B, RPW_B><<<GB, 256, 0, stream>>>(rp2B, b_ev, x16,
        basket16, out_basket, nullptr, nullptr, nullptr, N_BASKETS, NKEYPAD_B);
    k_spmm_win<0, W_I, RPW_I><<<GI, 256, 0, stream>>>(rp2I, i_ev, basket16,
        cur1_16, nullptr, nullptr, nullptr, nullptr, N_ITEMS, NKEYPAD_I);
    // -------- layer 2 --------
    k_spmm_win<2, W_B, RPW_B><<<GB, 256, 0, stream>>>(rp2B, b_ev, cur1_16,
        basket16, out_basket, nullptr, nullptr, nullptr, N_BASKETS, NKEYPAD_B);
    k_spmm_win<0, W_I, RPW_I><<<GI, 256, 0, stream>>>(rp2I, i_ev, basket16,
        cur2_16, nullptr, nullptr, nullptr, nullptr, N_ITEMS, NKEYPAD_I);
    // -------- layer 3 --------
    k_spmm_win<3, W_B, RPW_B><<<GB, 256, 0, stream>>>(rp2B, b_ev, cur2_16,
        basket16, out_basket, nullptr, nullptr, nullptr, N_BASKETS, NKEYPAD_B);
    k_spmm_win<4, W_I, RPW_I><<<GI, 256, 0, stream>>>(rp2I, i_ev, basket16,
        nullptr, out_item, x, cur1_16, cur2_16, N_ITEMS, NKEYPAD_I);
}